// Round 15
// baseline (146.071 us; speedup 1.0000x reference)
//
#include <hip/hip_runtime.h>
#include <hip/hip_bf16.h>

#define NPOS 4096
#define BB 2
#define KS2 32  // k-split for PV pass (128 keys per block)
#define QS2 32  // q-split for stats pass (128 q per block)

typedef short v4s __attribute__((ext_vector_type(4)));
typedef short v8s __attribute__((ext_vector_type(8)));
typedef float v4f __attribute__((ext_vector_type(4)));
typedef unsigned short ushort_t;

static __device__ __forceinline__ unsigned short f2bf(float f) {
    unsigned int u = __float_as_uint(f);
    return (unsigned short)((u + 0x7fffu + ((u >> 16) & 1u)) >> 16);
}
static __device__ __forceinline__ float bf2f(ushort_t s) {
    return __uint_as_float(((unsigned int)s) << 16);
}

__device__ __forceinline__ float pe_val(int C, int c, int ch, int h, int w) {
    int blk = ch / c;
    int j = ch - blk * c;
    int half = c >> 1;
    int jj = (j < half) ? j : j - half;
    float freq = __expf(-(2.0f * jj / (float)c) * 9.210340371976184f); // ln(10000)
    int pos = (blk < 2) ? h : w;   // torch-broadcast quirk: blocks 0,1 -> y(=h), block 2 -> z(=w)
    float s = (float)pos * freq;
    return (j < half) ? __sinf(s) : __cosf(s);
}

// pad_build with inline PE: Y (B,96,4096) fp32 -> Y_pad (B,18,18,18,96) bf16
__device__ __forceinline__ void pad_body(int r, const float* __restrict__ Y,
                                         ushort_t* __restrict__ Ypad) {
    __shared__ float tb[96 * 16];
    int t = threadIdx.x;
    for (int i = t; i < 96 * 16; i += 256) tb[i] = pe_val(96, 32, i >> 4, i & 15, i & 15);
    __syncthreads();
    int idx = r * 256 + t;
    if (idx >= BB * 5832 * 24) return;
    int ci4 = idx % 24;
    int cell = idx / 24;
    int wp = cell % 18; int c2 = cell / 18;
    int hp = c2 % 18; int c3 = c2 / 18;
    int zp = c3 % 18; int b = c3 / 18;
    ushort_t pk[4] = {0, 0, 0, 0};
    if (zp >= 1 && zp <= 16 && hp >= 1 && hp <= 16 && wp >= 1 && wp <= 16) {
        int n = (zp - 1) * 256 + (hp - 1) * 16 + (wp - 1);
        int h = hp - 1, w0 = wp - 1;
#pragma unroll
        for (int j = 0; j < 4; j++) {
            int ch = ci4 * 4 + j;
            float pe = tb[ch * 16 + (ch < 64 ? h : w0)];
            pk[j] = f2bf(Y[((size_t)(b * 96 + ch) << 12) + n] + pe);
        }
    }
    *(v4s*)&Ypad[(size_t)idx * 4] = *(v4s*)pk;
}

// conv1x1 + BN + ReLU with inline PE (co-split x8): in (B,CI,N)+PE -> out (B,N,48)
template<int CI, int CC>   // CC = c param of pe3d (16 for S, 32 for Y)
__device__ __forceinline__ void proj_body(int r, const float* __restrict__ in,
                                          const float* __restrict__ w, const float* __restrict__ bias,
                                          const float* __restrict__ g, const float* __restrict__ be,
                                          float* __restrict__ out) {
    int pc = r >> 3, cc = r & 7;
    int o0 = cc * 6;
    __shared__ float wl[6 * CI];
    __shared__ float tb[CI * 16];
    __shared__ float sb[6], bb[6];
    int t = threadIdx.x;
    for (int i = t; i < 6 * CI; i += 256) {
        int o = i / CI, ci = i - o * CI;
        wl[i] = w[(size_t)(o0 + o) * CI + ci];
    }
    for (int i = t; i < CI * 16; i += 256) tb[i] = pe_val(CI, CC, i >> 4, i & 15, i & 15);
    if (t < 6) {
        float s = g[o0 + t] * rsqrtf(1.0f + 1e-5f);
        sb[t] = s; bb[t] = bias[o0 + t] * s + be[o0 + t];
    }
    __syncthreads();
    int gn = pc * 256 + t;
    int b = gn >> 12;
    int n = gn & 4095;
    int h = (n >> 4) & 15, w0 = n & 15;
    const float* ip = in + (size_t)b * CI * NPOS + n;
    float acc[6];
#pragma unroll
    for (int o = 0; o < 6; o++) acc[o] = 0.f;
#pragma unroll
    for (int ci = 0; ci < CI; ci++) {
        float v = ip[(size_t)ci * NPOS] + tb[ci * 16 + (ci < 2 * CC ? h : w0)];
#pragma unroll
        for (int o = 0; o < 6; o++) acc[o] += v * wl[o * CI + ci];
    }
    float* op = out + (size_t)gn * 48 + o0;
#pragma unroll
    for (int o = 0; o < 6; o++) {
        float z = acc[o] * sb[o] + bb[o];
        op[o] = z > 0.f ? z : 0.f;
    }
}

// prep: pad_build | proj_s | proj_y | w3 repack, one launch
__global__ void prep_kernel(const float* __restrict__ S, const float* __restrict__ Y,
                            const float* __restrict__ w3,
                            const float* __restrict__ w_s, const float* __restrict__ b_s,
                            const float* __restrict__ g_s, const float* __restrict__ be_s,
                            const float* __restrict__ w_y, const float* __restrict__ b_y,
                            const float* __restrict__ g_y, const float* __restrict__ be_y,
                            ushort_t* __restrict__ Ypad, float* __restrict__ S1,
                            float* __restrict__ Y1, ushort_t* __restrict__ wr) {
    int bid = blockIdx.x;
    if (bid < 1094) {
        pad_body(bid, Y, Ypad);
    } else if (bid < 1350) {
        proj_body<48, 16>(bid - 1094, S, w_s, b_s, g_s, be_s, S1);
    } else if (bid < 1606) {
        proj_body<96, 32>(bid - 1350, Y, w_y, b_y, g_y, be_y, Y1);
    } else {
        int idx = (bid - 1606) * 256 + threadIdx.x; // 27*96*96
        if (idx < 27 * 96 * 96) {
            int ci = idx % 96;
            int t2 = idx / 96;
            int co = t2 % 96;
            int tap = t2 / 96;
            wr[idx] = f2bf(w3[(size_t)(co * 96 + ci) * 27 + tap]);
        }
    }
}

// Q,K,V co-split x8.  Q/K padded to d=64 (zeros in [48,64)).  grid 768.
__global__ void qkv_kernel(const float* __restrict__ Y1, const float* __restrict__ S1,
                           const float* __restrict__ Wq, const float* __restrict__ Wk,
                           const float* __restrict__ Wv, ushort_t* __restrict__ Qb,
                           ushort_t* __restrict__ Kb, ushort_t* __restrict__ Vt) {
    int grp = blockIdx.x >> 8;
    int r = blockIdx.x & 255;
    int pc = r >> 3, cc = r & 7;
    int o0 = cc * 6;
    const float* in = (grp == 2) ? S1 : Y1;
    const float* w = (grp == 0) ? Wq : (grp == 1) ? Wk : Wv;
    __shared__ float wl[48 * 6];   // [d][o]
    int t = threadIdx.x;
    for (int i = t; i < 48 * 6; i += 256) {
        int d = i / 6, o = i - d * 6;
        wl[i] = w[(size_t)d * 48 + o0 + o];
    }
    __syncthreads();
    int gn = pc * 256 + t;
    const float* ip = in + (size_t)gn * 48;
    float acc[6];
#pragma unroll
    for (int o = 0; o < 6; o++) acc[o] = 0.f;
#pragma unroll
    for (int d = 0; d < 48; d++) {
        float v = ip[d];
#pragma unroll
        for (int o = 0; o < 6; o++) acc[o] += v * wl[d * 6 + o];
    }
    if (grp < 2) {
        ushort_t* base = (grp == 0 ? Qb : Kb) + (size_t)gn * 64;
#pragma unroll
        for (int o = 0; o < 6; o++) base[o0 + o] = f2bf(acc[o]);
        if (cc == 0) {
            v8s z = {0, 0, 0, 0, 0, 0, 0, 0};
            *(v8s*)(base + 48) = z;
            *(v8s*)(base + 56) = z;
        }
    } else {
        int b = gn >> 12; int n = gn & 4095;
#pragma unroll
        for (int o = 0; o < 6; o++)
            Vt[((size_t)(b * 48 + o0 + o) << 12) + n] = f2bf(acc[o]);
    }
}

// Pass 1: column (over-q) exp-sum, 16x16x32 MFMA on d=64-padded Q/K.
// Wave owns 64 keys, streams 128 q.  grid: b(2) x kb(16) x qs(32) = 1024.
__global__ void attn_stats_mfma_kernel(const ushort_t* __restrict__ Qb,
                                       const ushort_t* __restrict__ Kb,
                                       float* __restrict__ ps) {
    int bid = blockIdx.x;
    int qs = bid & 31; int kb = (bid >> 5) & 15; int b = bid >> 9;
    int t = threadIdx.x; int wv = t >> 6; int lane = t & 63;
    int lr = lane & 15, g = lane >> 4;
    const float scale = 0.14433756729740643f;
    int key0 = kb * 256 + wv * 64;
    v8s ka[4][2];
#pragma unroll
    for (int kt = 0; kt < 4; kt++) {
        const ushort_t* krow = Kb + ((size_t)(b * NPOS + key0 + kt * 16 + lr)) * 64;
        ka[kt][0] = *(const v8s*)(krow + 8 * g);
        ka[kt][1] = *(const v8s*)(krow + 32 + 8 * g);
    }
    float s[4][4];
#pragma unroll
    for (int kt = 0; kt < 4; kt++)
#pragma unroll
        for (int r = 0; r < 4; r++) s[kt][r] = 0.f;
    for (int qt = 0; qt < 8; qt++) {
        int q = qs * 128 + qt * 16 + lr;
        const ushort_t* qrow = Qb + ((size_t)(b * NPOS + q)) * 64;
        v8s qf0 = *(const v8s*)(qrow + 8 * g);
        v8s qf1 = *(const v8s*)(qrow + 32 + 8 * g);
#pragma unroll
        for (int kt = 0; kt < 4; kt++) {
            v4f acc = {0.f, 0.f, 0.f, 0.f};
            acc = __builtin_amdgcn_mfma_f32_16x16x32_bf16(ka[kt][0], qf0, acc, 0, 0, 0);
            acc = __builtin_amdgcn_mfma_f32_16x16x32_bf16(ka[kt][1], qf1, acc, 0, 0, 0);
#pragma unroll
            for (int r = 0; r < 4; r++) s[kt][r] += __expf(acc[r] * scale);
        }
    }
#pragma unroll
    for (int off = 1; off < 16; off <<= 1)
#pragma unroll
        for (int kt = 0; kt < 4; kt++)
#pragma unroll
            for (int r = 0; r < 4; r++) s[kt][r] += __shfl_xor(s[kt][r], off);
    if (lr == 0) {
#pragma unroll
        for (int kt = 0; kt < 4; kt++) {
            int idx = (b * QS2 + qs) * NPOS + key0 + kt * 16 + 4 * g;
            v4f ss = {s[kt][0], s[kt][1], s[kt][2], s[kt][3]};
            *(v4f*)&ps[idx] = ss;
        }
    }
}

// PV body: 128 q x 128 keys per block (wave owns 32 q).  K LDS-staged
// (XOR-swizzled); V read直接 from L2 (768 KB resident — no LDS stage);
// colinv folded into p.  xpart bf16 (b,32,q,48).  2048 PV blocks.
__device__ __forceinline__ void pv_body(int bid, const ushort_t* __restrict__ Qb,
                                        const ushort_t* __restrict__ Kb,
                                        const ushort_t* __restrict__ Vt,
                                        const float* __restrict__ ps,
                                        ushort_t* __restrict__ xpart) {
    __shared__ ushort_t Kl[128 * 64];   // [key][64d], 16B-slot XOR swizzle (row&7)
    __shared__ float ciL[128];
    int ks = bid & 31; int qb = (bid >> 5) & 31; int b = bid >> 10;
    int t = threadIdx.x; int wv = t >> 6; int lane = t & 63;
    int lr = lane & 15, g = lane >> 4;
    const float scale = 0.14433756729740643f;
    int kb0 = ks * 128;
    // stage K: 1024 v8s, swizzled 16B slots
    {
        const ushort_t* src = Kb + ((size_t)(b * NPOS + kb0)) * 64;
        for (int i = t; i < 1024; i += 256) {
            int row = i >> 3, slot = i & 7;
            *(v8s*)&Kl[row * 64 + ((slot ^ (row & 7)) << 3)] =
                *(const v8s*)(src + row * 64 + slot * 8);
        }
        // colinv for this tile's 128 keys
        if (t < 128) {
            float s = 0.f;
#pragma unroll
            for (int qs = 0; qs < QS2; qs++)
                s += ps[(size_t)(b * QS2 + qs) * NPOS + kb0 + t];
            ciL[t] = 1.0f / s;
        }
    }
    int q0 = qb * 128 + wv * 32;
    v8s qf[2][2];
#pragma unroll
    for (int qt = 0; qt < 2; qt++) {
        const ushort_t* qrow = Qb + ((size_t)(b * NPOS + q0 + qt * 16 + lr)) * 64;
        qf[qt][0] = *(const v8s*)(qrow + 8 * g);
        qf[qt][1] = *(const v8s*)(qrow + 32 + 8 * g);
    }
    __syncthreads();
    v4f xacc[2][3];
#pragma unroll
    for (int qt = 0; qt < 2; qt++)
#pragma unroll
        for (int nt = 0; nt < 3; nt++) xacc[qt][nt] = (v4f){0.f, 0.f, 0.f, 0.f};
    for (int kt = 0; kt < 2; kt++) {
        v4s p[4][2];   // [tm][qt]
#pragma unroll
        for (int tm = 0; tm < 4; tm++) {
            int krow = kt * 64 + 16 * tm + lr;
            v8s ka0 = *(const v8s*)&Kl[krow * 64 + ((g ^ (krow & 7)) << 3)];
            v8s ka1 = *(const v8s*)&Kl[krow * 64 + (((4 + g) ^ (krow & 7)) << 3)];
            v4f ci = *(const v4f*)&ciL[kt * 64 + 16 * tm + 4 * g];
#pragma unroll
            for (int qt = 0; qt < 2; qt++) {
                v4f acc = {0.f, 0.f, 0.f, 0.f};
                acc = __builtin_amdgcn_mfma_f32_16x16x32_bf16(ka0, qf[qt][0], acc, 0, 0, 0);
                acc = __builtin_amdgcn_mfma_f32_16x16x32_bf16(ka1, qf[qt][1], acc, 0, 0, 0);
                v4s pp;
#pragma unroll
                for (int r = 0; r < 4; r++)
                    pp[r] = (short)f2bf(__expf(acc[r] * scale) * ci[r]);
                p[tm][qt] = pp;
            }
        }
#pragma unroll
        for (int nt = 0; nt < 3; nt++) {
            const ushort_t* vrow = Vt + ((size_t)(b * 48 + 16 * nt + lr) << 12) + kb0 + kt * 64;
#pragma unroll
            for (int tm = 0; tm < 4; tm++) {
                v4s vf = *(const v4s*)(vrow + 16 * tm + 4 * g);
#pragma unroll
                for (int qt = 0; qt < 2; qt++)
                    xacc[qt][nt] = __builtin_amdgcn_mfma_f32_16x16x16bf16_1k(
                        p[tm][qt], vf, xacc[qt][nt], 0, 0, 0);
            }
        }
    }
#pragma unroll
    for (int qt = 0; qt < 2; qt++)
#pragma unroll
        for (int nt = 0; nt < 3; nt++)
#pragma unroll
            for (int r = 0; r < 4; r++)
                xpart[(((size_t)(b * KS2 + ks) << 12) + q0 + qt * 16 + 4 * g + r) * 48 + 16 * nt + lr] =
                    f2bf(xacc[qt][nt][r]);
}

// conv body: implicit-GEMM 16x16x32 MFMA, 3 acc chains, burst register staging.
__device__ __forceinline__ void conv_body(int bid, const ushort_t* __restrict__ Ypad,
                                          const ushort_t* __restrict__ wr,
                                          const float* __restrict__ b3,
                                          float* __restrict__ Y3) {
    int b = bid / 384;
    int r = bid % 384;
    int cot = r % 6;
    int zhq = r / 6;                 // 0..63
    int t = threadIdx.x; int wv = t >> 6; int lane = t & 63;
    int z = zhq >> 2;
    int h = (zhq & 3) * 4 + wv;
    int lr = lane & 15, g = lane >> 4;
    v4f acc[3];
#pragma unroll
    for (int kd = 0; kd < 3; kd++) acc[kd] = (v4f){0.f, 0.f, 0.f, 0.f};
    const ushort_t* wbase = wr + (size_t)(cot * 16 + lr) * 96 + 8 * g;
#pragma unroll
    for (int kd = 0; kd < 3; kd++) {
#pragma unroll
        for (int kh = 0; kh < 3; kh++) {
            const ushort_t* arow = Ypad + (((size_t)(b * 18 + z + kd) * 18 + h + kh) * 18 + lr) * 96 + 8 * g;
            int tap0 = (kd * 3 + kh) * 3;
            v8s af[3][3], bf[3][3];
#pragma unroll
            for (int kw = 0; kw < 3; kw++)
#pragma unroll
                for (int c = 0; c < 3; c++) {
                    af[kw][c] = *(const v8s*)(arow + kw * 96 + c * 32);
                    bf[kw][c] = *(const v8s*)(wbase + (size_t)(tap0 + kw) * 96 * 96 + c * 32);
                }
#pragma unroll
            for (int kw = 0; kw < 3; kw++)
#pragma unroll
                for (int c = 0; c < 3; c++)
                    acc[kd] = __builtin_amdgcn_mfma_f32_16x16x32_bf16(
                        af[kw][c], bf[kw][c], acc[kd], 0, 0, 0);
        }
    }
    float bv = b3[cot * 16 + lr];
    int pos = z * 256 + h * 16 + 4 * g;
#pragma unroll
    for (int r2 = 0; r2 < 4; r2++)
        Y3[(((size_t)b << 12) + pos + r2) * 96 + cot * 16 + lr] =
            acc[0][r2] + acc[1][r2] + acc[2][r2] + bv;
}

// merged PV + conv3d, interleaved: 2816 = 11*256 groups of {8 PV, 3 conv}.
__global__ void pvconv_kernel(const ushort_t* __restrict__ Qb, const ushort_t* __restrict__ Kb,
                              const ushort_t* __restrict__ Vt, const float* __restrict__ ps,
                              ushort_t* __restrict__ xpart,
                              const ushort_t* __restrict__ Ypad, const ushort_t* __restrict__ wr,
                              const float* __restrict__ b3, float* __restrict__ Y3) {
    int g11 = blockIdx.x / 11, r11 = blockIdx.x % 11;
    if (r11 < 8) pv_body(g11 * 8 + r11, Qb, Kb, Vt, ps, xpart);
    else conv_body(g11 * 3 + (r11 - 8), Ypad, wr, b3, Y3);
}

// Reduce xpart over ks ONCE: (b,ks,q,48) bf16 -> xsum (b,q,48) fp32.
__global__ void xreduce_kernel(const ushort_t* __restrict__ xpart, float* __restrict__ xsum) {
    int v = blockIdx.x * 256 + threadIdx.x;     // over BB*NPOS*6
    if (v >= BB * NPOS * 6) return;
    int b = v / (NPOS * 6);
    int rem8 = (v - b * NPOS * 6) * 8;
    float s[8];
#pragma unroll
    for (int j = 0; j < 8; j++) s[j] = 0.f;
    const ushort_t* base = xpart + (size_t)b * KS2 * NPOS * 48 + rem8;
#pragma unroll 4
    for (int ks = 0; ks < KS2; ks++) {
        v8s x = *(const v8s*)(base + (size_t)ks * NPOS * 48);
#pragma unroll
        for (int j = 0; j < 8; j++) s[j] += bf2f((ushort_t)x[j]);
    }
    float* op = xsum + (size_t)b * NPOS * 48 + rem8;
    v4f lo = {s[0], s[1], s[2], s[3]};
    v4f hi = {s[4], s[5], s[6], s[7]};
    *(v4f*)op = lo;
    *(v4f*)(op + 4) = hi;
}

// z_out body: xsum + conv1x1(w_o) + BN + ReLU, * (S + PE inline) -> ch [0,48)
__device__ __forceinline__ void z_out_body(int r, const float* __restrict__ xsum,
                                           const float* __restrict__ w_o, const float* __restrict__ b_o,
                                           const float* __restrict__ g_o, const float* __restrict__ be_o,
                                           const float* __restrict__ S, float* __restrict__ out) {
    int pc = r >> 3, cc = r & 7;
    int o0 = cc * 6;
    __shared__ float wl[6 * 48];
    __shared__ float tbz[6 * 16];
    __shared__ float sb[6], bb[6];
    int t = threadIdx.x;
    for (int i = t; i < 6 * 48; i += 256) {
        int o = i / 48, d = i - o * 48;
        wl[i] = w_o[(size_t)(o0 + o) * 48 + d];
    }
    if (t < 96) tbz[t] = pe_val(48, 16, o0 + t / 16, t & 15, t & 15);
    if (t < 6) {
        float s = g_o[o0 + t] * rsqrtf(1.f + 1e-5f);
        sb[t] = s; bb[t] = b_o[o0 + t] * s + be_o[o0 + t];
    }
    __syncthreads();
    int gn = pc * 256 + t;
    int b = gn >> 12; int n = gn & 4095;
    int h = (n >> 4) & 15, w0 = n & 15;
    const v4f* p = (const v4f*)(xsum + (size_t)gn * 48);
    float x[48];
#pragma unroll
    for (int d4 = 0; d4 < 12; d4++) {
        v4f v = p[d4];
#pragma unroll
        for (int j = 0; j < 4; j++) x[d4 * 4 + j] = v[j];
    }
#pragma unroll
    for (int o = 0; o < 6; o++) {
        float acc = 0.f;
#pragma unroll
        for (int d = 0; d < 48; d++) acc += wl[o * 48 + d] * x[d];
        float z = acc * sb[o] + bb[o];
        z = z > 0.f ? z : 0.f;
        float spe = S[((size_t)b * 48 + o0 + o) * NPOS + n] +
                    tbz[o * 16 + (o0 + o < 32 ? h : w0)];
        out[((size_t)b * 96 + o0 + o) * NPOS + n] = z * spe;
    }
}

// y2 body: conv1x1(w_y2) + BN + ReLU on Y3 (B,4096,96) -> out ch [48,96)
__device__ __forceinline__ void y2_out_body(int r, const float* __restrict__ Y3,
                                            const float* __restrict__ w_y2, const float* __restrict__ b_y2,
                                            const float* __restrict__ g_y2, const float* __restrict__ be_y2,
                                            float* __restrict__ out) {
    int pc = r >> 3, cc = r & 7;
    int o0 = cc * 6;
    __shared__ float wl2[6 * 96];
    __shared__ float sb2[6], bb2[6];
    int t = threadIdx.x;
    for (int i = t; i < 6 * 96; i += 256) {
        int o = i / 96, ci = i - o * 96;
        wl2[i] = w_y2[(size_t)(o0 + o) * 96 + ci];
    }
    if (t < 6) {
        float s = g_y2[o0 + t] * rsqrtf(1.f + 1e-5f);
        sb2[t] = s; bb2[t] = b_y2[o0 + t] * s + be_y2[o0 + t];
    }
    __syncthreads();
    int gn = pc * 256 + t;
    int b = gn >> 12; int n = gn & 4095;
    const v4f* ip = (const v4f*)(Y3 + (size_t)gn * 96);
    float acc[6];
#pragma unroll
    for (int o = 0; o < 6; o++) acc[o] = 0.f;
#pragma unroll
    for (int c4 = 0; c4 < 24; c4++) {
        v4f v = ip[c4];
#pragma unroll
        for (int j = 0; j < 4; j++)
#pragma unroll
            for (int o = 0; o < 6; o++) acc[o] += v[j] * wl2[o * 96 + c4 * 4 + j];
    }
#pragma unroll
    for (int o = 0; o < 6; o++) {
        float z = acc[o] * sb2[o] + bb2[o];
        out[((size_t)b * 96 + 48 + o0 + o) * NPOS + n] = z > 0.f ? z : 0.f;
    }
}

__global__ void zy_out_kernel(const float* __restrict__ xsum, const float* __restrict__ w_o,
                              const float* __restrict__ b_o, const float* __restrict__ g_o,
                              const float* __restrict__ be_o, const float* __restrict__ S,
                              const float* __restrict__ Y3, const float* __restrict__ w_y2,
                              const float* __restrict__ b_y2, const float* __restrict__ g_y2,
                              const float* __restrict__ be_y2, float* __restrict__ out) {
    int bid = blockIdx.x;
    if (bid < 256) z_out_body(bid, xsum, w_o, b_o, g_o, be_o, S, out);
    else y2_out_body(bid - 256, Y3, w_y2, b_y2, g_y2, be_y2, out);
}

extern "C" void kernel_launch(void* const* d_in, const int* in_sizes, int n_in,
                              void* d_out, int out_size, void* d_ws, size_t ws_size,
                              hipStream_t stream) {
    const float* Y    = (const float*)d_in[0];
    const float* S    = (const float*)d_in[1];
    const float* w_s  = (const float*)d_in[2];
    const float* b_s  = (const float*)d_in[3];
    const float* g_s  = (const float*)d_in[4];
    const float* be_s = (const float*)d_in[5];
    const float* w_y  = (const float*)d_in[6];
    const float* b_y  = (const float*)d_in[7];
    const float* g_y  = (const float*)d_in[8];
    const float* be_y = (const float*)d_in[9];
    const float* Wq   = (const float*)d_in[10];
    const float* Wk   = (const float*)d_in[11];
    const float* Wv   = (const float*)d_in[12];
    const float* w_o  = (const float*)d_in[13];
    const float* b_o  = (const float*)d_in[14];
    const float* g_o  = (const float*)d_in[15];
    const float* be_o = (const float*)d_in[16];
    const float* w3   = (const float*)d_in[17];
    const float* b3   = (const float*)d_in[18];
    const float* w_y2 = (const float*)d_in[19];
    const float* b_y2 = (const float*)d_in[20];
    const float* g_y2 = (const float*)d_in[21];
    const float* be_y2= (const float*)d_in[22];
    float* out = (float*)d_out;

    float* ws = (float*)d_ws;
    float* S1     = ws;                           // 393216 f
    float* Y1     = ws + 393216;                  // 393216 f
    ushort_t* Qb  = (ushort_t*)(ws + 786432);     // (B,N,64) bf16 = 262144 f
    ushort_t* Kb  = (ushort_t*)(ws + 1048576);    // 262144 f
    ushort_t* Vt  = (ushort_t*)(ws + 1310720);    // (B,48,N) bf16 = 196608 f
    float* ps     = ws + 1507328;                 // 2*32*4096 = 262144 f
    ushort_t* xpart = (ushort_t*)(ws + 1769472);  // bf16 (b,32,q,48) = 6291456 f
    float* xsum   = ws + 8060928;                 // (b,q,48) fp32 = 393216 f
    float* Y3     = ws + 8454144;                 // (b,n,96) = 786432 f
    ushort_t* Ypad= (ushort_t*)(ws + 9240576);    // 559872 f
    ushort_t* wr  = (ushort_t*)(ws + 9800448);    // 124416 f

    // 1. pad_build | proj_s | proj_y | w3 repack (PE inline)
    prep_kernel<<<2578, 256, 0, stream>>>(S, Y, w3, w_s, b_s, g_s, be_s,
                                          w_y, b_y, g_y, be_y, Ypad, S1, Y1, wr);
    // 2. Q,K (d=64-padded) and V^T, bf16
    qkv_kernel<<<768, 256, 0, stream>>>(Y1, S1, Wq, Wk, Wv, Qb, Kb, Vt);
    // 3. column exp-sum (softmax over q; shift-invariant, no max)
    attn_stats_mfma_kernel<<<BB * 16 * QS2, 256, 0, stream>>>(Qb, Kb, ps);
    // 4. merged+interleaved: PV partials (colinv folded) | 3x3x3 conv
    pvconv_kernel<<<2816, 256, 0, stream>>>(Qb, Kb, Vt, ps, xpart, Ypad, wr, b3, Y3);
    // 5. reduce xpart over ks (once)
    xreduce_kernel<<<192, 256, 0, stream>>>(xpart, xsum);
    // 6. both output halves (z uses S + PE inline)
    zy_out_kernel<<<512, 256, 0, stream>>>(xsum, w_o, b_o, g_o, be_o, S,
                                           Y3, w_y2, b_y2, g_y2, be_y2, out);
}

// Round 16
// 135.587 us; speedup vs baseline: 1.0773x; 1.0773x over previous
//
#include <hip/hip_runtime.h>
#include <hip/hip_bf16.h>

#define NPOS 4096
#define BB 2
#define KS2 32  // k-split for PV pass (128 keys per block, single LDS tile)
#define QS2 32  // q-split for stats pass (128 q per block)

typedef short v4s __attribute__((ext_vector_type(4)));
typedef short v8s __attribute__((ext_vector_type(8)));
typedef float v4f __attribute__((ext_vector_type(4)));
typedef unsigned short ushort_t;

static __device__ __forceinline__ unsigned short f2bf(float f) {
    unsigned int u = __float_as_uint(f);
    return (unsigned short)((u + 0x7fffu + ((u >> 16) & 1u)) >> 16);
}
static __device__ __forceinline__ float bf2f(ushort_t s) {
    return __uint_as_float(((unsigned int)s) << 16);
}

__device__ __forceinline__ float pe_val(int C, int c, int ch, int h, int w) {
    int blk = ch / c;
    int j = ch - blk * c;
    int half = c >> 1;
    int jj = (j < half) ? j : j - half;
    float freq = __expf(-(2.0f * jj / (float)c) * 9.210340371976184f); // ln(10000)
    int pos = (blk < 2) ? h : w;   // torch-broadcast quirk: blocks 0,1 -> y(=h), block 2 -> z(=w)
    float s = (float)pos * freq;
    return (j < half) ? __sinf(s) : __cosf(s);
}

// pad_build with inline PE: Y (B,96,4096) fp32 -> Y_pad (B,18,18,18,96) bf16
__device__ __forceinline__ void pad_body(int r, const float* __restrict__ Y,
                                         ushort_t* __restrict__ Ypad) {
    __shared__ float tb[96 * 16];
    int t = threadIdx.x;
    for (int i = t; i < 96 * 16; i += 256) tb[i] = pe_val(96, 32, i >> 4, i & 15, i & 15);
    __syncthreads();
    int idx = r * 256 + t;
    if (idx >= BB * 5832 * 24) return;
    int ci4 = idx % 24;
    int cell = idx / 24;
    int wp = cell % 18; int c2 = cell / 18;
    int hp = c2 % 18; int c3 = c2 / 18;
    int zp = c3 % 18; int b = c3 / 18;
    ushort_t pk[4] = {0, 0, 0, 0};
    if (zp >= 1 && zp <= 16 && hp >= 1 && hp <= 16 && wp >= 1 && wp <= 16) {
        int n = (zp - 1) * 256 + (hp - 1) * 16 + (wp - 1);
        int h = hp - 1, w0 = wp - 1;
#pragma unroll
        for (int j = 0; j < 4; j++) {
            int ch = ci4 * 4 + j;
            float pe = tb[ch * 16 + (ch < 64 ? h : w0)];
            pk[j] = f2bf(Y[((size_t)(b * 96 + ch) << 12) + n] + pe);
        }
    }
    *(v4s*)&Ypad[(size_t)idx * 4] = *(v4s*)pk;
}

// conv1x1 + BN + ReLU with inline PE (co-split x8): in (B,CI,N)+PE -> out (B,N,48)
template<int CI, int CC>
__device__ __forceinline__ void proj_body(int r, const float* __restrict__ in,
                                          const float* __restrict__ w, const float* __restrict__ bias,
                                          const float* __restrict__ g, const float* __restrict__ be,
                                          float* __restrict__ out) {
    int pc = r >> 3, cc = r & 7;
    int o0 = cc * 6;
    __shared__ float wl[6 * CI];
    __shared__ float tb[CI * 16];
    __shared__ float sb[6], bb[6];
    int t = threadIdx.x;
    for (int i = t; i < 6 * CI; i += 256) {
        int o = i / CI, ci = i - o * CI;
        wl[i] = w[(size_t)(o0 + o) * CI + ci];
    }
    for (int i = t; i < CI * 16; i += 256) tb[i] = pe_val(CI, CC, i >> 4, i & 15, i & 15);
    if (t < 6) {
        float s = g[o0 + t] * rsqrtf(1.0f + 1e-5f);
        sb[t] = s; bb[t] = bias[o0 + t] * s + be[o0 + t];
    }
    __syncthreads();
    int gn = pc * 256 + t;
    int b = gn >> 12;
    int n = gn & 4095;
    int h = (n >> 4) & 15, w0 = n & 15;
    const float* ip = in + (size_t)b * CI * NPOS + n;
    float acc[6];
#pragma unroll
    for (int o = 0; o < 6; o++) acc[o] = 0.f;
#pragma unroll
    for (int ci = 0; ci < CI; ci++) {
        float v = ip[(size_t)ci * NPOS] + tb[ci * 16 + (ci < 2 * CC ? h : w0)];
#pragma unroll
        for (int o = 0; o < 6; o++) acc[o] += v * wl[o * CI + ci];
    }
    float* op = out + (size_t)gn * 48 + o0;
#pragma unroll
    for (int o = 0; o < 6; o++) {
        float z = acc[o] * sb[o] + bb[o];
        op[o] = z > 0.f ? z : 0.f;
    }
}

// prep: pad_build | proj_s | proj_y | w3 repack, one launch
__global__ void prep_kernel(const float* __restrict__ S, const float* __restrict__ Y,
                            const float* __restrict__ w3,
                            const float* __restrict__ w_s, const float* __restrict__ b_s,
                            const float* __restrict__ g_s, const float* __restrict__ be_s,
                            const float* __restrict__ w_y, const float* __restrict__ b_y,
                            const float* __restrict__ g_y, const float* __restrict__ be_y,
                            ushort_t* __restrict__ Ypad, float* __restrict__ S1,
                            float* __restrict__ Y1, ushort_t* __restrict__ wr) {
    int bid = blockIdx.x;
    if (bid < 1094) {
        pad_body(bid, Y, Ypad);
    } else if (bid < 1350) {
        proj_body<48, 16>(bid - 1094, S, w_s, b_s, g_s, be_s, S1);
    } else if (bid < 1606) {
        proj_body<96, 32>(bid - 1350, Y, w_y, b_y, g_y, be_y, Y1);
    } else {
        int idx = (bid - 1606) * 256 + threadIdx.x; // 27*96*96
        if (idx < 27 * 96 * 96) {
            int ci = idx % 96;
            int t2 = idx / 96;
            int co = t2 % 96;
            int tap = t2 / 96;
            wr[idx] = f2bf(w3[(size_t)(co * 96 + ci) * 27 + tap]);
        }
    }
}

// Q,K,V co-split x8.  Q/K padded to d=64 (zeros in [48,64)).  grid 768.
__global__ void qkv_kernel(const float* __restrict__ Y1, const float* __restrict__ S1,
                           const float* __restrict__ Wq, const float* __restrict__ Wk,
                           const float* __restrict__ Wv, ushort_t* __restrict__ Qb,
                           ushort_t* __restrict__ Kb, ushort_t* __restrict__ Vt) {
    int grp = blockIdx.x >> 8;
    int r = blockIdx.x & 255;
    int pc = r >> 3, cc = r & 7;
    int o0 = cc * 6;
    const float* in = (grp == 2) ? S1 : Y1;
    const float* w = (grp == 0) ? Wq : (grp == 1) ? Wk : Wv;
    __shared__ float wl[48 * 6];   // [d][o]
    int t = threadIdx.x;
    for (int i = t; i < 48 * 6; i += 256) {
        int d = i / 6, o = i - d * 6;
        wl[i] = w[(size_t)d * 48 + o0 + o];
    }
    __syncthreads();
    int gn = pc * 256 + t;
    const float* ip = in + (size_t)gn * 48;
    float acc[6];
#pragma unroll
    for (int o = 0; o < 6; o++) acc[o] = 0.f;
#pragma unroll
    for (int d = 0; d < 48; d++) {
        float v = ip[d];
#pragma unroll
        for (int o = 0; o < 6; o++) acc[o] += v * wl[d * 6 + o];
    }
    if (grp < 2) {
        ushort_t* base = (grp == 0 ? Qb : Kb) + (size_t)gn * 64;
#pragma unroll
        for (int o = 0; o < 6; o++) base[o0 + o] = f2bf(acc[o]);
        if (cc == 0) {
            v8s z = {0, 0, 0, 0, 0, 0, 0, 0};
            *(v8s*)(base + 48) = z;
            *(v8s*)(base + 56) = z;
        }
    } else {
        int b = gn >> 12; int n = gn & 4095;
#pragma unroll
        for (int o = 0; o < 6; o++)
            Vt[((size_t)(b * 48 + o0 + o) << 12) + n] = f2bf(acc[o]);
    }
}

// Pass 1: column (over-q) exp-sum, 16x16x32 MFMA on d=64-padded Q/K.
// Wave owns 64 keys, streams 128 q.  grid: b(2) x kb(16) x qs(32) = 1024.
__global__ void attn_stats_mfma_kernel(const ushort_t* __restrict__ Qb,
                                       const ushort_t* __restrict__ Kb,
                                       float* __restrict__ ps) {
    int bid = blockIdx.x;
    int qs = bid & 31; int kb = (bid >> 5) & 15; int b = bid >> 9;
    int t = threadIdx.x; int wv = t >> 6; int lane = t & 63;
    int lr = lane & 15, g = lane >> 4;
    const float scale = 0.14433756729740643f;
    int key0 = kb * 256 + wv * 64;
    v8s ka[4][2];
#pragma unroll
    for (int kt = 0; kt < 4; kt++) {
        const ushort_t* krow = Kb + ((size_t)(b * NPOS + key0 + kt * 16 + lr)) * 64;
        ka[kt][0] = *(const v8s*)(krow + 8 * g);
        ka[kt][1] = *(const v8s*)(krow + 32 + 8 * g);
    }
    float s[4][4];
#pragma unroll
    for (int kt = 0; kt < 4; kt++)
#pragma unroll
        for (int r = 0; r < 4; r++) s[kt][r] = 0.f;
    for (int qt = 0; qt < 8; qt++) {
        int q = qs * 128 + qt * 16 + lr;
        const ushort_t* qrow = Qb + ((size_t)(b * NPOS + q)) * 64;
        v8s qf0 = *(const v8s*)(qrow + 8 * g);
        v8s qf1 = *(const v8s*)(qrow + 32 + 8 * g);
#pragma unroll
        for (int kt = 0; kt < 4; kt++) {
            v4f acc = {0.f, 0.f, 0.f, 0.f};
            acc = __builtin_amdgcn_mfma_f32_16x16x32_bf16(ka[kt][0], qf0, acc, 0, 0, 0);
            acc = __builtin_amdgcn_mfma_f32_16x16x32_bf16(ka[kt][1], qf1, acc, 0, 0, 0);
#pragma unroll
            for (int r = 0; r < 4; r++) s[kt][r] += __expf(acc[r] * scale);
        }
    }
#pragma unroll
    for (int off = 1; off < 16; off <<= 1)
#pragma unroll
        for (int kt = 0; kt < 4; kt++)
#pragma unroll
            for (int r = 0; r < 4; r++) s[kt][r] += __shfl_xor(s[kt][r], off);
    if (lr == 0) {
#pragma unroll
        for (int kt = 0; kt < 4; kt++) {
            int idx = (b * QS2 + qs) * NPOS + key0 + kt * 16 + 4 * g;
            v4f ss = {s[kt][0], s[kt][1], s[kt][2], s[kt][3]};
            *(v4f*)&ps[idx] = ss;
        }
    }
}

// PV body with LDS-staged K/V (XOR-swizzled), single 128-key tile, colinv
// folded into p.  Wave owns 64 q.  xpart bf16 d-major (b,ks,48,4096):
// lane's 4 consecutive-q values pack into one v4s 8B store (store coalescing).
__device__ __forceinline__ void pv_body(int bid, const ushort_t* __restrict__ Qb,
                                        const ushort_t* __restrict__ Kb,
                                        const ushort_t* __restrict__ Vt,
                                        const float* __restrict__ ps,
                                        ushort_t* __restrict__ xpart) {
    __shared__ ushort_t Kl[128 * 64];   // [key][64d], 16B-slot XOR swizzle (row&7)
    __shared__ ushort_t Vl[48 * 128];   // [d][128k], 8B-slot XOR swizzle (row&15)
    __shared__ float ciL[128];
    int ks = bid & 31; int qb = (bid >> 5) & 15; int b = bid >> 9;
    int t = threadIdx.x; int wv = t >> 6; int lane = t & 63;
    int lr = lane & 15, g = lane >> 4;
    const float scale = 0.14433756729740643f;
    int kb0 = ks * 128;
    // stage K: 1024 v8s, swizzled 16B slots
    {
        const ushort_t* src = Kb + ((size_t)(b * NPOS + kb0)) * 64;
        for (int i = t; i < 1024; i += 256) {
            int row = i >> 3, slot = i & 7;
            *(v8s*)&Kl[row * 64 + ((slot ^ (row & 7)) << 3)] =
                *(const v8s*)(src + row * 64 + slot * 8);
        }
        // stage V: 1536 v4s, swizzled 8B slots
        const ushort_t* vsrc = Vt + ((size_t)(b * 48) << 12) + kb0;
        for (int i = t; i < 1536; i += 256) {
            int row = i >> 5, s8 = i & 31;
            *(v4s*)&Vl[row * 128 + ((s8 ^ (row & 15)) << 2)] =
                *(const v4s*)(vsrc + ((size_t)row << 12) + s8 * 4);
        }
        // colinv for this tile's 128 keys
        if (t < 128) {
            float s = 0.f;
#pragma unroll
            for (int qs = 0; qs < QS2; qs++)
                s += ps[(size_t)(b * QS2 + qs) * NPOS + kb0 + t];
            ciL[t] = 1.0f / s;
        }
    }
    int q0 = qb * 256 + wv * 64;
    v8s qf[4][2];
#pragma unroll
    for (int qt = 0; qt < 4; qt++) {
        const ushort_t* qrow = Qb + ((size_t)(b * NPOS + q0 + qt * 16 + lr)) * 64;
        qf[qt][0] = *(const v8s*)(qrow + 8 * g);
        qf[qt][1] = *(const v8s*)(qrow + 32 + 8 * g);
    }
    __syncthreads();
    v4f xacc[4][3];
#pragma unroll
    for (int qt = 0; qt < 4; qt++)
#pragma unroll
        for (int nt = 0; nt < 3; nt++) xacc[qt][nt] = (v4f){0.f, 0.f, 0.f, 0.f};
    for (int kt = 0; kt < 2; kt++) {
        v4s p[4][4];   // [tm][qt]
#pragma unroll
        for (int tm = 0; tm < 4; tm++) {
            int krow = kt * 64 + 16 * tm + lr;
            v8s ka0 = *(const v8s*)&Kl[krow * 64 + ((g ^ (krow & 7)) << 3)];
            v8s ka1 = *(const v8s*)&Kl[krow * 64 + (((4 + g) ^ (krow & 7)) << 3)];
            v4f ci = *(const v4f*)&ciL[kt * 64 + 16 * tm + 4 * g];
#pragma unroll
            for (int qt = 0; qt < 4; qt++) {
                v4f acc = {0.f, 0.f, 0.f, 0.f};
                acc = __builtin_amdgcn_mfma_f32_16x16x32_bf16(ka0, qf[qt][0], acc, 0, 0, 0);
                acc = __builtin_amdgcn_mfma_f32_16x16x32_bf16(ka1, qf[qt][1], acc, 0, 0, 0);
                v4s pp;
#pragma unroll
                for (int r = 0; r < 4; r++)
                    pp[r] = (short)f2bf(__expf(acc[r] * scale) * ci[r]);
                p[tm][qt] = pp;
            }
        }
#pragma unroll
        for (int nt = 0; nt < 3; nt++) {
#pragma unroll
            for (int tm = 0; tm < 4; tm++) {
                int vrowd = 16 * nt + lr;
                int s8 = 16 * kt + 4 * tm + g;
                v4s vf = *(const v4s*)&Vl[vrowd * 128 + ((s8 ^ (vrowd & 15)) << 2)];
#pragma unroll
                for (int qt = 0; qt < 4; qt++)
                    xacc[qt][nt] = __builtin_amdgcn_mfma_f32_16x16x16bf16_1k(
                        p[tm][qt], vf, xacc[qt][nt], 0, 0, 0);
            }
        }
    }
    // d-major xpart: addr = ((b*KS2+ks)*48 + 16nt+lr)*4096 + q0+qt*16+4g  (+r contiguous)
#pragma unroll
    for (int qt = 0; qt < 4; qt++)
#pragma unroll
        for (int nt = 0; nt < 3; nt++) {
            v4s pk;
#pragma unroll
            for (int r = 0; r < 4; r++) pk[r] = (short)f2bf(xacc[qt][nt][r]);
            *(v4s*)&xpart[(((size_t)(b * KS2 + ks) * 48) + 16 * nt + lr) * NPOS +
                          q0 + qt * 16 + 4 * g] = pk;
        }
}

// conv body: implicit-GEMM 16x16x32 MFMA, 3 acc chains, burst register staging.
__device__ __forceinline__ void conv_body(int bid, const ushort_t* __restrict__ Ypad,
                                          const ushort_t* __restrict__ wr,
                                          const float* __restrict__ b3,
                                          float* __restrict__ Y3) {
    int b = bid / 384;
    int r = bid % 384;
    int cot = r % 6;
    int zhq = r / 6;                 // 0..63
    int t = threadIdx.x; int wv = t >> 6; int lane = t & 63;
    int z = zhq >> 2;
    int h = (zhq & 3) * 4 + wv;
    int lr = lane & 15, g = lane >> 4;
    v4f acc[3];
#pragma unroll
    for (int kd = 0; kd < 3; kd++) acc[kd] = (v4f){0.f, 0.f, 0.f, 0.f};
    const ushort_t* wbase = wr + (size_t)(cot * 16 + lr) * 96 + 8 * g;
#pragma unroll
    for (int kd = 0; kd < 3; kd++) {
#pragma unroll
        for (int kh = 0; kh < 3; kh++) {
            const ushort_t* arow = Ypad + (((size_t)(b * 18 + z + kd) * 18 + h + kh) * 18 + lr) * 96 + 8 * g;
            int tap0 = (kd * 3 + kh) * 3;
            v8s af[3][3], bf[3][3];
#pragma unroll
            for (int kw = 0; kw < 3; kw++)
#pragma unroll
                for (int c = 0; c < 3; c++) {
                    af[kw][c] = *(const v8s*)(arow + kw * 96 + c * 32);
                    bf[kw][c] = *(const v8s*)(wbase + (size_t)(tap0 + kw) * 96 * 96 + c * 32);
                }
#pragma unroll
            for (int kw = 0; kw < 3; kw++)
#pragma unroll
                for (int c = 0; c < 3; c++)
                    acc[kd] = __builtin_amdgcn_mfma_f32_16x16x32_bf16(
                        af[kw][c], bf[kw][c], acc[kd], 0, 0, 0);
        }
    }
    float bv = b3[cot * 16 + lr];
    int pos = z * 256 + h * 16 + 4 * g;
#pragma unroll
    for (int r2 = 0; r2 < 4; r2++)
        Y3[(((size_t)b << 12) + pos + r2) * 96 + cot * 16 + lr] =
            acc[0][r2] + acc[1][r2] + acc[2][r2] + bv;
}

// merged PV + conv3d, interleaved 4:3 (1792 = 7*256), with bijective XCD
// swizzle (1792 = 8 XCDs x 224) for per-XCD L2 tile locality.
__global__ void pvconv_kernel(const ushort_t* __restrict__ Qb, const ushort_t* __restrict__ Kb,
                              const ushort_t* __restrict__ Vt, const float* __restrict__ ps,
                              ushort_t* __restrict__ xpart,
                              const ushort_t* __restrict__ Ypad, const ushort_t* __restrict__ wr,
                              const float* __restrict__ b3, float* __restrict__ Y3) {
    int bid = (blockIdx.x & 7) * 224 + (blockIdx.x >> 3);   // XCD-contiguous chunks
    int g7 = bid / 7, r7 = bid % 7;
    if (r7 < 4) pv_body(g7 * 4 + r7, Qb, Kb, Vt, ps, xpart);
    else conv_body(g7 * 3 + (r7 - 4), Ypad, wr, b3, Y3);
}

// Reduce xpart over ks ONCE (flat per-slice; layout-agnostic) -> xsum d-major
// (b,48,4096) fp32.
__global__ void xreduce_kernel(const ushort_t* __restrict__ xpart, float* __restrict__ xsum) {
    int v = blockIdx.x * 256 + threadIdx.x;     // over BB*NPOS*6
    if (v >= BB * NPOS * 6) return;
    int b = v / (NPOS * 6);
    int rem8 = (v - b * NPOS * 6) * 8;
    float s[8];
#pragma unroll
    for (int j = 0; j < 8; j++) s[j] = 0.f;
    const ushort_t* base = xpart + (size_t)b * KS2 * NPOS * 48 + rem8;
#pragma unroll 4
    for (int ks = 0; ks < KS2; ks++) {
        v8s x = *(const v8s*)(base + (size_t)ks * NPOS * 48);
#pragma unroll
        for (int j = 0; j < 8; j++) s[j] += bf2f((ushort_t)x[j]);
    }
    float* op = xsum + (size_t)b * NPOS * 48 + rem8;
    v4f lo = {s[0], s[1], s[2], s[3]};
    v4f hi = {s[4], s[5], s[6], s[7]};
    *(v4f*)op = lo;
    *(v4f*)(op + 4) = hi;
}

// z_out body: xsum d-major (b,48,4096) + conv1x1(w_o) + BN + ReLU, * (S+PE) -> ch [0,48)
__device__ __forceinline__ void z_out_body(int r, const float* __restrict__ xsum,
                                           const float* __restrict__ w_o, const float* __restrict__ b_o,
                                           const float* __restrict__ g_o, const float* __restrict__ be_o,
                                           const float* __restrict__ S, float* __restrict__ out) {
    int pc = r >> 3, cc = r & 7;
    int o0 = cc * 6;
    __shared__ float wl[6 * 48];
    __shared__ float tbz[6 * 16];
    __shared__ float sb[6], bb[6];
    int t = threadIdx.x;
    for (int i = t; i < 6 * 48; i += 256) {
        int o = i / 48, d = i - o * 48;
        wl[i] = w_o[(size_t)(o0 + o) * 48 + d];
    }
    if (t < 96) tbz[t] = pe_val(48, 16, o0 + t / 16, t & 15, t & 15);
    if (t < 6) {
        float s = g_o[o0 + t] * rsqrtf(1.f + 1e-5f);
        sb[t] = s; bb[t] = b_o[o0 + t] * s + be_o[o0 + t];
    }
    __syncthreads();
    int gn = pc * 256 + t;
    int b = gn >> 12; int n = gn & 4095;
    int h = (n >> 4) & 15, w0 = n & 15;
    const float* xp = xsum + ((size_t)b * 48 << 12) + n;
    float x[48];
#pragma unroll
    for (int d = 0; d < 48; d++) x[d] = xp[(size_t)d << 12];
#pragma unroll
    for (int o = 0; o < 6; o++) {
        float acc = 0.f;
#pragma unroll
        for (int d = 0; d < 48; d++) acc += wl[o * 48 + d] * x[d];
        float z = acc * sb[o] + bb[o];
        z = z > 0.f ? z : 0.f;
        float spe = S[((size_t)b * 48 + o0 + o) * NPOS + n] +
                    tbz[o * 16 + (o0 + o < 32 ? h : w0)];
        out[((size_t)b * 96 + o0 + o) * NPOS + n] = z * spe;
    }
}

// y2 body: conv1x1(w_y2) + BN + ReLU on Y3 (B,4096,96) -> out ch [48,96)
__device__ __forceinline__ void y2_out_body(int r, const float* __restrict__ Y3,
                                            const float* __restrict__ w_y2, const float* __restrict__ b_y2,
                                            const float* __restrict__ g_y2, const float* __restrict__ be_y2,
                                            float* __restrict__ out) {
    int pc = r >> 3, cc = r & 7;
    int o0 = cc * 6;
    __shared__ float wl2[6 * 96];
    __shared__ float sb2[6], bb2[6];
    int t = threadIdx.x;
    for (int i = t; i < 6 * 96; i += 256) {
        int o = i / 96, ci = i - o * 96;
        wl2[i] = w_y2[(size_t)(o0 + o) * 96 + ci];
    }
    if (t < 6) {
        float s = g_y2[o0 + t] * rsqrtf(1.f + 1e-5f);
        sb2[t] = s; bb2[t] = b_y2[o0 + t] * s + be_y2[o0 + t];
    }
    __syncthreads();
    int gn = pc * 256 + t;
    int b = gn >> 12; int n = gn & 4095;
    const v4f* ip = (const v4f*)(Y3 + (size_t)gn * 96);
    float acc[6];
#pragma unroll
    for (int o = 0; o < 6; o++) acc[o] = 0.f;
#pragma unroll
    for (int c4 = 0; c4 < 24; c4++) {
        v4f v = ip[c4];
#pragma unroll
        for (int j = 0; j < 4; j++)
#pragma unroll
            for (int o = 0; o < 6; o++) acc[o] += v[j] * wl2[o * 96 + c4 * 4 + j];
    }
#pragma unroll
    for (int o = 0; o < 6; o++) {
        float z = acc[o] * sb2[o] + bb2[o];
        out[((size_t)b * 96 + 48 + o0 + o) * NPOS + n] = z > 0.f ? z : 0.f;
    }
}

__global__ void zy_out_kernel(const float* __restrict__ xsum, const float* __restrict__ w_o,
                              const float* __restrict__ b_o, const float* __restrict__ g_o,
                              const float* __restrict__ be_o, const float* __restrict__ S,
                              const float* __restrict__ Y3, const float* __restrict__ w_y2,
                              const float* __restrict__ b_y2, const float* __restrict__ g_y2,
                              const float* __restrict__ be_y2, float* __restrict__ out) {
    int bid = blockIdx.x;
    if (bid < 256) z_out_body(bid, xsum, w_o, b_o, g_o, be_o, S, out);
    else y2_out_body(bid - 256, Y3, w_y2, b_y2, g_y2, be_y2, out);
}

extern "C" void kernel_launch(void* const* d_in, const int* in_sizes, int n_in,
                              void* d_out, int out_size, void* d_ws, size_t ws_size,
                              hipStream_t stream) {
    const float* Y    = (const float*)d_in[0];
    const float* S    = (const float*)d_in[1];
    const float* w_s  = (const float*)d_in[2];
    const float* b_s  = (const float*)d_in[3];
    const float* g_s  = (const float*)d_in[4];
    const float* be_s = (const float*)d_in[5];
    const float* w_y  = (const float*)d_in[6];
    const float* b_y  = (const float*)d_in[7];
    const float* g_y  = (const float*)d_in[8];
    const float* be_y = (const float*)d_in[9];
    const float* Wq   = (const float*)d_in[10];
    const float* Wk   = (const float*)d_in[11];
    const float* Wv   = (const float*)d_in[12];
    const float* w_o  = (const float*)d_in[13];
    const float* b_o  = (const float*)d_in[14];
    const float* g_o  = (const float*)d_in[15];
    const float* be_o = (const float*)d_in[16];
    const float* w3   = (const float*)d_in[17];
    const float* b3   = (const float*)d_in[18];
    const float* w_y2 = (const float*)d_in[19];
    const float* b_y2 = (const float*)d_in[20];
    const float* g_y2 = (const float*)d_in[21];
    const float* be_y2= (const float*)d_in[22];
    float* out = (float*)d_out;

    float* ws = (float*)d_ws;
    float* S1     = ws;                           // 393216 f
    float* Y1     = ws + 393216;                  // 393216 f
    ushort_t* Qb  = (ushort_t*)(ws + 786432);     // (B,N,64) bf16 = 262144 f
    ushort_t* Kb  = (ushort_t*)(ws + 1048576);    // 262144 f
    ushort_t* Vt  = (ushort_t*)(ws + 1310720);    // (B,48,N) bf16 = 196608 f
    float* ps     = ws + 1507328;                 // 2*32*4096 = 262144 f
    ushort_t* xpart = (ushort_t*)(ws + 1769472);  // bf16 (b,32,48,4096) = 6291456 f
    float* xsum   = ws + 8060928;                 // (b,48,4096) fp32 = 393216 f
    float* Y3     = ws + 8454144;                 // (b,n,96) = 786432 f
    ushort_t* Ypad= (ushort_t*)(ws + 9240576);    // 559872 f
    ushort_t* wr  = (ushort_t*)(ws + 9800448);    // 124416 f

    // 1. pad_build | proj_s | proj_y | w3 repack (PE inline)
    prep_kernel<<<2578, 256, 0, stream>>>(S, Y, w3, w_s, b_s, g_s, be_s,
                                          w_y, b_y, g_y, be_y, Ypad, S1, Y1, wr);
    // 2. Q,K (d=64-padded) and V^T, bf16
    qkv_kernel<<<768, 256, 0, stream>>>(Y1, S1, Wq, Wk, Wv, Qb, Kb, Vt);
    // 3. column exp-sum (softmax over q; shift-invariant, no max)
    attn_stats_mfma_kernel<<<BB * 16 * QS2, 256, 0, stream>>>(Qb, Kb, ps);
    // 4. merged+interleaved: PV partials (colinv folded) | 3x3x3 conv, XCD swizzle
    pvconv_kernel<<<1792, 256, 0, stream>>>(Qb, Kb, Vt, ps, xpart, Ypad, wr, b3, Y3);
    // 5. reduce xpart over ks (once)
    xreduce_kernel<<<192, 256, 0, stream>>>(xpart, xsum);
    // 6. both output halves (z uses S + PE inline, xsum d-major)
    zy_out_kernel<<<512, 256, 0, stream>>>(xsum, w_o, b_o, g_o, be_o, S,
                                           Y3, w_y2, b_y2, g_y2, be_y2, out);
}

// Round 17
// 128.067 us; speedup vs baseline: 1.1406x; 1.0587x over previous
//
#include <hip/hip_runtime.h>
#include <hip/hip_bf16.h>

#define NPOS 4096
#define BB 2
#define KS2 32  // k-split for PV pass (128 keys per block, single LDS tile)
#define QS2 32  // q-split for stats pass (128 q per block)

typedef short v4s __attribute__((ext_vector_type(4)));
typedef short v8s __attribute__((ext_vector_type(8)));
typedef float v4f __attribute__((ext_vector_type(4)));
typedef unsigned short ushort_t;

static __device__ __forceinline__ unsigned short f2bf(float f) {
    unsigned int u = __float_as_uint(f);
    return (unsigned short)((u + 0x7fffu + ((u >> 16) & 1u)) >> 16);
}
static __device__ __forceinline__ float bf2f(ushort_t s) {
    return __uint_as_float(((unsigned int)s) << 16);
}

__device__ __forceinline__ float pe_val(int C, int c, int ch, int h, int w) {
    int blk = ch / c;
    int j = ch - blk * c;
    int half = c >> 1;
    int jj = (j < half) ? j : j - half;
    float freq = __expf(-(2.0f * jj / (float)c) * 9.210340371976184f); // ln(10000)
    int pos = (blk < 2) ? h : w;   // torch-broadcast quirk: blocks 0,1 -> y(=h), block 2 -> z(=w)
    float s = (float)pos * freq;
    return (j < half) ? __sinf(s) : __cosf(s);
}

// pad_build with inline PE: Y (B,96,4096) fp32 -> Y_pad (B,18,18,18,96) bf16
__device__ __forceinline__ void pad_body(int r, const float* __restrict__ Y,
                                         ushort_t* __restrict__ Ypad) {
    __shared__ float tb[96 * 16];
    int t = threadIdx.x;
    for (int i = t; i < 96 * 16; i += 256) tb[i] = pe_val(96, 32, i >> 4, i & 15, i & 15);
    __syncthreads();
    int idx = r * 256 + t;
    if (idx >= BB * 5832 * 24) return;
    int ci4 = idx % 24;
    int cell = idx / 24;
    int wp = cell % 18; int c2 = cell / 18;
    int hp = c2 % 18; int c3 = c2 / 18;
    int zp = c3 % 18; int b = c3 / 18;
    ushort_t pk[4] = {0, 0, 0, 0};
    if (zp >= 1 && zp <= 16 && hp >= 1 && hp <= 16 && wp >= 1 && wp <= 16) {
        int n = (zp - 1) * 256 + (hp - 1) * 16 + (wp - 1);
        int h = hp - 1, w0 = wp - 1;
#pragma unroll
        for (int j = 0; j < 4; j++) {
            int ch = ci4 * 4 + j;
            float pe = tb[ch * 16 + (ch < 64 ? h : w0)];
            pk[j] = f2bf(Y[((size_t)(b * 96 + ch) << 12) + n] + pe);
        }
    }
    *(v4s*)&Ypad[(size_t)idx * 4] = *(v4s*)pk;
}

// conv1x1 + BN + ReLU with inline PE (co-split x8): in (B,CI,N)+PE -> out (B,N,48)
template<int CI, int CC>   // CC = c param of pe3d (16 for S, 32 for Y)
__device__ __forceinline__ void proj_body(int r, const float* __restrict__ in,
                                          const float* __restrict__ w, const float* __restrict__ bias,
                                          const float* __restrict__ g, const float* __restrict__ be,
                                          float* __restrict__ out) {
    int pc = r >> 3, cc = r & 7;
    int o0 = cc * 6;
    __shared__ float wl[6 * CI];
    __shared__ float tb[CI * 16];
    __shared__ float sb[6], bb[6];
    int t = threadIdx.x;
    for (int i = t; i < 6 * CI; i += 256) {
        int o = i / CI, ci = i - o * CI;
        wl[i] = w[(size_t)(o0 + o) * CI + ci];
    }
    for (int i = t; i < CI * 16; i += 256) tb[i] = pe_val(CI, CC, i >> 4, i & 15, i & 15);
    if (t < 6) {
        float s = g[o0 + t] * rsqrtf(1.0f + 1e-5f);
        sb[t] = s; bb[t] = bias[o0 + t] * s + be[o0 + t];
    }
    __syncthreads();
    int gn = pc * 256 + t;
    int b = gn >> 12;
    int n = gn & 4095;
    int h = (n >> 4) & 15, w0 = n & 15;
    const float* ip = in + (size_t)b * CI * NPOS + n;
    float acc[6];
#pragma unroll
    for (int o = 0; o < 6; o++) acc[o] = 0.f;
#pragma unroll
    for (int ci = 0; ci < CI; ci++) {
        float v = ip[(size_t)ci * NPOS] + tb[ci * 16 + (ci < 2 * CC ? h : w0)];
#pragma unroll
        for (int o = 0; o < 6; o++) acc[o] += v * wl[o * CI + ci];
    }
    float* op = out + (size_t)gn * 48 + o0;
#pragma unroll
    for (int o = 0; o < 6; o++) {
        float z = acc[o] * sb[o] + bb[o];
        op[o] = z > 0.f ? z : 0.f;
    }
}

// prep: pad_build | proj_s | proj_y | w3 repack, one launch
__global__ void prep_kernel(const float* __restrict__ S, const float* __restrict__ Y,
                            const float* __restrict__ w3,
                            const float* __restrict__ w_s, const float* __restrict__ b_s,
                            const float* __restrict__ g_s, const float* __restrict__ be_s,
                            const float* __restrict__ w_y, const float* __restrict__ b_y,
                            const float* __restrict__ g_y, const float* __restrict__ be_y,
                            ushort_t* __restrict__ Ypad, float* __restrict__ S1,
                            float* __restrict__ Y1, ushort_t* __restrict__ wr) {
    int bid = blockIdx.x;
    if (bid < 1094) {
        pad_body(bid, Y, Ypad);
    } else if (bid < 1350) {
        proj_body<48, 16>(bid - 1094, S, w_s, b_s, g_s, be_s, S1);
    } else if (bid < 1606) {
        proj_body<96, 32>(bid - 1350, Y, w_y, b_y, g_y, be_y, Y1);
    } else {
        int idx = (bid - 1606) * 256 + threadIdx.x; // 27*96*96
        if (idx < 27 * 96 * 96) {
            int ci = idx % 96;
            int t2 = idx / 96;
            int co = t2 % 96;
            int tap = t2 / 96;
            wr[idx] = f2bf(w3[(size_t)(co * 96 + ci) * 27 + tap]);
        }
    }
}

// Q,K,V co-split x8.  Q/K padded to d=64 (zeros in [48,64)).  grid 768.
__global__ void qkv_kernel(const float* __restrict__ Y1, const float* __restrict__ S1,
                           const float* __restrict__ Wq, const float* __restrict__ Wk,
                           const float* __restrict__ Wv, ushort_t* __restrict__ Qb,
                           ushort_t* __restrict__ Kb, ushort_t* __restrict__ Vt) {
    int grp = blockIdx.x >> 8;
    int r = blockIdx.x & 255;
    int pc = r >> 3, cc = r & 7;
    int o0 = cc * 6;
    const float* in = (grp == 2) ? S1 : Y1;
    const float* w = (grp == 0) ? Wq : (grp == 1) ? Wk : Wv;
    __shared__ float wl[48 * 6];   // [d][o]
    int t = threadIdx.x;
    for (int i = t; i < 48 * 6; i += 256) {
        int d = i / 6, o = i - d * 6;
        wl[i] = w[(size_t)d * 48 + o0 + o];
    }
    __syncthreads();
    int gn = pc * 256 + t;
    const float* ip = in + (size_t)gn * 48;
    float acc[6];
#pragma unroll
    for (int o = 0; o < 6; o++) acc[o] = 0.f;
#pragma unroll
    for (int d = 0; d < 48; d++) {
        float v = ip[d];
#pragma unroll
        for (int o = 0; o < 6; o++) acc[o] += v * wl[d * 6 + o];
    }
    if (grp < 2) {
        ushort_t* base = (grp == 0 ? Qb : Kb) + (size_t)gn * 64;
#pragma unroll
        for (int o = 0; o < 6; o++) base[o0 + o] = f2bf(acc[o]);
        if (cc == 0) {
            v8s z = {0, 0, 0, 0, 0, 0, 0, 0};
            *(v8s*)(base + 48) = z;
            *(v8s*)(base + 56) = z;
        }
    } else {
        int b = gn >> 12; int n = gn & 4095;
#pragma unroll
        for (int o = 0; o < 6; o++)
            Vt[((size_t)(b * 48 + o0 + o) << 12) + n] = f2bf(acc[o]);
    }
}

// Pass 1: column (over-q) exp-sum, 16x16x32 MFMA on d=64-padded Q/K.
// Wave owns 64 keys, streams 128 q.  grid: b(2) x kb(16) x qs(32) = 1024.
__global__ void attn_stats_mfma_kernel(const ushort_t* __restrict__ Qb,
                                       const ushort_t* __restrict__ Kb,
                                       float* __restrict__ ps) {
    int bid = blockIdx.x;
    int qs = bid & 31; int kb = (bid >> 5) & 15; int b = bid >> 9;
    int t = threadIdx.x; int wv = t >> 6; int lane = t & 63;
    int lr = lane & 15, g = lane >> 4;
    const float scale = 0.14433756729740643f;
    int key0 = kb * 256 + wv * 64;
    v8s ka[4][2];
#pragma unroll
    for (int kt = 0; kt < 4; kt++) {
        const ushort_t* krow = Kb + ((size_t)(b * NPOS + key0 + kt * 16 + lr)) * 64;
        ka[kt][0] = *(const v8s*)(krow + 8 * g);
        ka[kt][1] = *(const v8s*)(krow + 32 + 8 * g);
    }
    float s[4][4];
#pragma unroll
    for (int kt = 0; kt < 4; kt++)
#pragma unroll
        for (int r = 0; r < 4; r++) s[kt][r] = 0.f;
    for (int qt = 0; qt < 8; qt++) {
        int q = qs * 128 + qt * 16 + lr;
        const ushort_t* qrow = Qb + ((size_t)(b * NPOS + q)) * 64;
        v8s qf0 = *(const v8s*)(qrow + 8 * g);
        v8s qf1 = *(const v8s*)(qrow + 32 + 8 * g);
#pragma unroll
        for (int kt = 0; kt < 4; kt++) {
            v4f acc = {0.f, 0.f, 0.f, 0.f};
            acc = __builtin_amdgcn_mfma_f32_16x16x32_bf16(ka[kt][0], qf0, acc, 0, 0, 0);
            acc = __builtin_amdgcn_mfma_f32_16x16x32_bf16(ka[kt][1], qf1, acc, 0, 0, 0);
#pragma unroll
            for (int r = 0; r < 4; r++) s[kt][r] += __expf(acc[r] * scale);
        }
    }
#pragma unroll
    for (int off = 1; off < 16; off <<= 1)
#pragma unroll
        for (int kt = 0; kt < 4; kt++)
#pragma unroll
            for (int r = 0; r < 4; r++) s[kt][r] += __shfl_xor(s[kt][r], off);
    if (lr == 0) {
#pragma unroll
        for (int kt = 0; kt < 4; kt++) {
            int idx = (b * QS2 + qs) * NPOS + key0 + kt * 16 + 4 * g;
            v4f ss = {s[kt][0], s[kt][1], s[kt][2], s[kt][3]};
            *(v4f*)&ps[idx] = ss;
        }
    }
}

// PV body with LDS-staged K/V (XOR-swizzled), single 128-key tile, colinv
// folded into p.  Wave owns 64 q.  xpart bf16 (b,32,q,48).
__device__ __forceinline__ void pv_body(int bid, const ushort_t* __restrict__ Qb,
                                        const ushort_t* __restrict__ Kb,
                                        const ushort_t* __restrict__ Vt,
                                        const float* __restrict__ ps,
                                        ushort_t* __restrict__ xpart) {
    __shared__ ushort_t Kl[128 * 64];   // [key][64d], 16B-slot XOR swizzle (row&7)
    __shared__ ushort_t Vl[48 * 128];   // [d][128k], 8B-slot XOR swizzle (row&15)
    __shared__ float ciL[128];
    int ks = bid & 31; int qb = (bid >> 5) & 15; int b = bid >> 9;
    int t = threadIdx.x; int wv = t >> 6; int lane = t & 63;
    int lr = lane & 15, g = lane >> 4;
    const float scale = 0.14433756729740643f;
    int kb0 = ks * 128;
    // stage K: 1024 v8s, swizzled 16B slots
    {
        const ushort_t* src = Kb + ((size_t)(b * NPOS + kb0)) * 64;
        for (int i = t; i < 1024; i += 256) {
            int row = i >> 3, slot = i & 7;
            *(v8s*)&Kl[row * 64 + ((slot ^ (row & 7)) << 3)] =
                *(const v8s*)(src + row * 64 + slot * 8);
        }
        // stage V: 1536 v4s, swizzled 8B slots
        const ushort_t* vsrc = Vt + ((size_t)(b * 48) << 12) + kb0;
        for (int i = t; i < 1536; i += 256) {
            int row = i >> 5, s8 = i & 31;
            *(v4s*)&Vl[row * 128 + ((s8 ^ (row & 15)) << 2)] =
                *(const v4s*)(vsrc + ((size_t)row << 12) + s8 * 4);
        }
        // colinv for this tile's 128 keys
        if (t < 128) {
            float s = 0.f;
#pragma unroll
            for (int qs = 0; qs < QS2; qs++)
                s += ps[(size_t)(b * QS2 + qs) * NPOS + kb0 + t];
            ciL[t] = 1.0f / s;
        }
    }
    int q0 = qb * 256 + wv * 64;
    v8s qf[4][2];
#pragma unroll
    for (int qt = 0; qt < 4; qt++) {
        const ushort_t* qrow = Qb + ((size_t)(b * NPOS + q0 + qt * 16 + lr)) * 64;
        qf[qt][0] = *(const v8s*)(qrow + 8 * g);
        qf[qt][1] = *(const v8s*)(qrow + 32 + 8 * g);
    }
    __syncthreads();
    v4f xacc[4][3];
#pragma unroll
    for (int qt = 0; qt < 4; qt++)
#pragma unroll
        for (int nt = 0; nt < 3; nt++) xacc[qt][nt] = (v4f){0.f, 0.f, 0.f, 0.f};
    for (int kt = 0; kt < 2; kt++) {
        v4s p[4][4];   // [tm][qt]
#pragma unroll
        for (int tm = 0; tm < 4; tm++) {
            int krow = kt * 64 + 16 * tm + lr;
            v8s ka0 = *(const v8s*)&Kl[krow * 64 + ((g ^ (krow & 7)) << 3)];
            v8s ka1 = *(const v8s*)&Kl[krow * 64 + (((4 + g) ^ (krow & 7)) << 3)];
            v4f ci = *(const v4f*)&ciL[kt * 64 + 16 * tm + 4 * g];
#pragma unroll
            for (int qt = 0; qt < 4; qt++) {
                v4f acc = {0.f, 0.f, 0.f, 0.f};
                acc = __builtin_amdgcn_mfma_f32_16x16x32_bf16(ka0, qf[qt][0], acc, 0, 0, 0);
                acc = __builtin_amdgcn_mfma_f32_16x16x32_bf16(ka1, qf[qt][1], acc, 0, 0, 0);
                v4s pp;
#pragma unroll
                for (int r = 0; r < 4; r++)
                    pp[r] = (short)f2bf(__expf(acc[r] * scale) * ci[r]);
                p[tm][qt] = pp;
            }
        }
#pragma unroll
        for (int nt = 0; nt < 3; nt++) {
#pragma unroll
            for (int tm = 0; tm < 4; tm++) {
                int vrowd = 16 * nt + lr;
                int s8 = 16 * kt + 4 * tm + g;
                v4s vf = *(const v4s*)&Vl[vrowd * 128 + ((s8 ^ (vrowd & 15)) << 2)];
#pragma unroll
                for (int qt = 0; qt < 4; qt++)
                    xacc[qt][nt] = __builtin_amdgcn_mfma_f32_16x16x16bf16_1k(
                        p[tm][qt], vf, xacc[qt][nt], 0, 0, 0);
            }
        }
    }
#pragma unroll
    for (int qt = 0; qt < 4; qt++)
#pragma unroll
        for (int nt = 0; nt < 3; nt++)
#pragma unroll
            for (int r = 0; r < 4; r++)
                xpart[(((size_t)(b * KS2 + ks) << 12) + q0 + qt * 16 + 4 * g + r) * 48 + 16 * nt + lr] =
                    f2bf(xacc[qt][nt][r]);
}

// conv body: implicit-GEMM 16x16x32 MFMA, 3 acc chains, burst register staging.
__device__ __forceinline__ void conv_body(int bid, const ushort_t* __restrict__ Ypad,
                                          const ushort_t* __restrict__ wr,
                                          const float* __restrict__ b3,
                                          float* __restrict__ Y3) {
    int b = bid / 384;
    int r = bid % 384;
    int cot = r % 6;
    int zhq = r / 6;                 // 0..63
    int t = threadIdx.x; int wv = t >> 6; int lane = t & 63;
    int z = zhq >> 2;
    int h = (zhq & 3) * 4 + wv;
    int lr = lane & 15, g = lane >> 4;
    v4f acc[3];
#pragma unroll
    for (int kd = 0; kd < 3; kd++) acc[kd] = (v4f){0.f, 0.f, 0.f, 0.f};
    const ushort_t* wbase = wr + (size_t)(cot * 16 + lr) * 96 + 8 * g;
#pragma unroll
    for (int kd = 0; kd < 3; kd++) {
#pragma unroll
        for (int kh = 0; kh < 3; kh++) {
            const ushort_t* arow = Ypad + (((size_t)(b * 18 + z + kd) * 18 + h + kh) * 18 + lr) * 96 + 8 * g;
            int tap0 = (kd * 3 + kh) * 3;
            v8s af[3][3], bf[3][3];
#pragma unroll
            for (int kw = 0; kw < 3; kw++)
#pragma unroll
                for (int c = 0; c < 3; c++) {
                    af[kw][c] = *(const v8s*)(arow + kw * 96 + c * 32);
                    bf[kw][c] = *(const v8s*)(wbase + (size_t)(tap0 + kw) * 96 * 96 + c * 32);
                }
#pragma unroll
            for (int kw = 0; kw < 3; kw++)
#pragma unroll
                for (int c = 0; c < 3; c++)
                    acc[kd] = __builtin_amdgcn_mfma_f32_16x16x32_bf16(
                        af[kw][c], bf[kw][c], acc[kd], 0, 0, 0);
        }
    }
    float bv = b3[cot * 16 + lr];
    int pos = z * 256 + h * 16 + 4 * g;
#pragma unroll
    for (int r2 = 0; r2 < 4; r2++)
        Y3[(((size_t)b << 12) + pos + r2) * 96 + cot * 16 + lr] =
            acc[0][r2] + acc[1][r2] + acc[2][r2] + bv;
}

// merged PV + conv3d, interleaved: 1792 = 7*256 groups of {4 PV, 3 conv}.
__global__ __launch_bounds__(256, 4)
void pvconv_kernel(const ushort_t* __restrict__ Qb, const ushort_t* __restrict__ Kb,
                   const ushort_t* __restrict__ Vt, const float* __restrict__ ps,
                   ushort_t* __restrict__ xpart,
                   const ushort_t* __restrict__ Ypad, const ushort_t* __restrict__ wr,
                   const float* __restrict__ b3, float* __restrict__ Y3) {
    int g7 = blockIdx.x / 7, r7 = blockIdx.x % 7;
    if (r7 < 4) pv_body(g7 * 4 + r7, Qb, Kb, Vt, ps, xpart);
    else conv_body(g7 * 3 + (r7 - 4), Ypad, wr, b3, Y3);
}

// Reduce xpart over ks ONCE: (b,ks,q,48) bf16 -> xsum (b,q,48) fp32.
__global__ void xreduce_kernel(const ushort_t* __restrict__ xpart, float* __restrict__ xsum) {
    int v = blockIdx.x * 256 + threadIdx.x;     // over BB*NPOS*6
    if (v >= BB * NPOS * 6) return;
    int b = v / (NPOS * 6);
    int rem8 = (v - b * NPOS * 6) * 8;
    float s[8];
#pragma unroll
    for (int j = 0; j < 8; j++) s[j] = 0.f;
    const ushort_t* base = xpart + (size_t)b * KS2 * NPOS * 48 + rem8;
#pragma unroll 4
    for (int ks = 0; ks < KS2; ks++) {
        v8s x = *(const v8s*)(base + (size_t)ks * NPOS * 48);
#pragma unroll
        for (int j = 0; j < 8; j++) s[j] += bf2f((ushort_t)x[j]);
    }
    float* op = xsum + (size_t)b * NPOS * 48 + rem8;
    v4f lo = {s[0], s[1], s[2], s[3]};
    v4f hi = {s[4], s[5], s[6], s[7]};
    *(v4f*)op = lo;
    *(v4f*)(op + 4) = hi;
}

// z_out body: xsum + conv1x1(w_o) + BN + ReLU, * (S + PE inline) -> ch [0,48)
__device__ __forceinline__ void z_out_body(int r, const float* __restrict__ xsum,
                                           const float* __restrict__ w_o, const float* __restrict__ b_o,
                                           const float* __restrict__ g_o, const float* __restrict__ be_o,
                                           const float* __restrict__ S, float* __restrict__ out) {
    int pc = r >> 3, cc = r & 7;
    int o0 = cc * 6;
    __shared__ float wl[6 * 48];
    __shared__ float tbz[6 * 16];
    __shared__ float sb[6], bb[6];
    int t = threadIdx.x;
    for (int i = t; i < 6 * 48; i += 256) {
        int o = i / 48, d = i - o * 48;
        wl[i] = w_o[(size_t)(o0 + o) * 48 + d];
    }
    if (t < 96) tbz[t] = pe_val(48, 16, o0 + t / 16, t & 15, t & 15);
    if (t < 6) {
        float s = g_o[o0 + t] * rsqrtf(1.f + 1e-5f);
        sb[t] = s; bb[t] = b_o[o0 + t] * s + be_o[o0 + t];
    }
    __syncthreads();
    int gn = pc * 256 + t;
    int b = gn >> 12; int n = gn & 4095;
    int h = (n >> 4) & 15, w0 = n & 15;
    const v4f* p = (const v4f*)(xsum + (size_t)gn * 48);
    float x[48];
#pragma unroll
    for (int d4 = 0; d4 < 12; d4++) {
        v4f v = p[d4];
#pragma unroll
        for (int j = 0; j < 4; j++) x[d4 * 4 + j] = v[j];
    }
#pragma unroll
    for (int o = 0; o < 6; o++) {
        float acc = 0.f;
#pragma unroll
        for (int d = 0; d < 48; d++) acc += wl[o * 48 + d] * x[d];
        float z = acc * sb[o] + bb[o];
        z = z > 0.f ? z : 0.f;
        float spe = S[((size_t)b * 48 + o0 + o) * NPOS + n] +
                    tbz[o * 16 + (o0 + o < 32 ? h : w0)];
        out[((size_t)b * 96 + o0 + o) * NPOS + n] = z * spe;
    }
}

// y2 body: conv1x1(w_y2) + BN + ReLU on Y3 (B,4096,96) -> out ch [48,96)
__device__ __forceinline__ void y2_out_body(int r, const float* __restrict__ Y3,
                                            const float* __restrict__ w_y2, const float* __restrict__ b_y2,
                                            const float* __restrict__ g_y2, const float* __restrict__ be_y2,
                                            float* __restrict__ out) {
    int pc = r >> 3, cc = r & 7;
    int o0 = cc * 6;
    __shared__ float wl2[6 * 96];
    __shared__ float sb2[6], bb2[6];
    int t = threadIdx.x;
    for (int i = t; i < 6 * 96; i += 256) {
        int o = i / 96, ci = i - o * 96;
        wl2[i] = w_y2[(size_t)(o0 + o) * 96 + ci];
    }
    if (t < 6) {
        float s = g_y2[o0 + t] * rsqrtf(1.f + 1e-5f);
        sb2[t] = s; bb2[t] = b_y2[o0 + t] * s + be_y2[o0 + t];
    }
    __syncthreads();
    int gn = pc * 256 + t;
    int b = gn >> 12; int n = gn & 4095;
    const v4f* ip = (const v4f*)(Y3 + (size_t)gn * 96);
    float acc[6];
#pragma unroll
    for (int o = 0; o < 6; o++) acc[o] = 0.f;
#pragma unroll
    for (int c4 = 0; c4 < 24; c4++) {
        v4f v = ip[c4];
#pragma unroll
        for (int j = 0; j < 4; j++)
#pragma unroll
            for (int o = 0; o < 6; o++) acc[o] += v[j] * wl2[o * 96 + c4 * 4 + j];
    }
#pragma unroll
    for (int o = 0; o < 6; o++) {
        float z = acc[o] * sb2[o] + bb2[o];
        out[((size_t)b * 96 + 48 + o0 + o) * NPOS + n] = z > 0.f ? z : 0.f;
    }
}

__global__ void zy_out_kernel(const float* __restrict__ xsum, const float* __restrict__ w_o,
                              const float* __restrict__ b_o, const float* __restrict__ g_o,
                              const float* __restrict__ be_o, const float* __restrict__ S,
                              const float* __restrict__ Y3, const float* __restrict__ w_y2,
                              const float* __restrict__ b_y2, const float* __restrict__ g_y2,
                              const float* __restrict__ be_y2, float* __restrict__ out) {
    int bid = blockIdx.x;
    if (bid < 256) z_out_body(bid, xsum, w_o, b_o, g_o, be_o, S, out);
    else y2_out_body(bid - 256, Y3, w_y2, b_y2, g_y2, be_y2, out);
}

extern "C" void kernel_launch(void* const* d_in, const int* in_sizes, int n_in,
                              void* d_out, int out_size, void* d_ws, size_t ws_size,
                              hipStream_t stream) {
    const float* Y    = (const float*)d_in[0];
    const float* S    = (const float*)d_in[1];
    const float* w_s  = (const float*)d_in[2];
    const float* b_s  = (const float*)d_in[3];
    const float* g_s  = (const float*)d_in[4];
    const float* be_s = (const float*)d_in[5];
    const float* w_y  = (const float*)d_in[6];
    const float* b_y  = (const float*)d_in[7];
    const float* g_y  = (const float*)d_in[8];
    const float* be_y = (const float*)d_in[9];
    const float* Wq   = (const float*)d_in[10];
    const float* Wk   = (const float*)d_in[11];
    const float* Wv   = (const float*)d_in[12];
    const float* w_o  = (const float*)d_in[13];
    const float* b_o  = (const float*)d_in[14];
    const float* g_o  = (const float*)d_in[15];
    const float* be_o = (const float*)d_in[16];
    const float* w3   = (const float*)d_in[17];
    const float* b3   = (const float*)d_in[18];
    const float* w_y2 = (const float*)d_in[19];
    const float* b_y2 = (const float*)d_in[20];
    const float* g_y2 = (const float*)d_in[21];
    const float* be_y2= (const float*)d_in[22];
    float* out = (float*)d_out;

    float* ws = (float*)d_ws;
    float* S1     = ws;                           // 393216 f
    float* Y1     = ws + 393216;                  // 393216 f
    ushort_t* Qb  = (ushort_t*)(ws + 786432);     // (B,N,64) bf16 = 262144 f
    ushort_t* Kb  = (ushort_t*)(ws + 1048576);    // 262144 f
    ushort_t* Vt  = (ushort_t*)(ws + 1310720);    // (B,48,N) bf16 = 196608 f
    float* ps     = ws + 1507328;                 // 2*32*4096 = 262144 f
    ushort_t* xpart = (ushort_t*)(ws + 1769472);  // bf16 (b,32,q,48) = 6291456 f
    float* xsum   = ws + 8060928;                 // (b,q,48) fp32 = 393216 f
    float* Y3     = ws + 8454144;                 // (b,n,96) = 786432 f
    ushort_t* Ypad= (ushort_t*)(ws + 9240576);    // 559872 f
    ushort_t* wr  = (ushort_t*)(ws + 9800448);    // 124416 f

    // 1. pad_build | proj_s | proj_y | w3 repack (PE inline)
    prep_kernel<<<2578, 256, 0, stream>>>(S, Y, w3, w_s, b_s, g_s, be_s,
                                          w_y, b_y, g_y, be_y, Ypad, S1, Y1, wr);
    // 2. Q,K (d=64-padded) and V^T, bf16
    qkv_kernel<<<768, 256, 0, stream>>>(Y1, S1, Wq, Wk, Wv, Qb, Kb, Vt);
    // 3. column exp-sum (softmax over q; shift-invariant, no max)
    attn_stats_mfma_kernel<<<BB * 16 * QS2, 256, 0, stream>>>(Qb, Kb, ps);
    // 4. merged+interleaved: PV partials (colinv folded) | 3x3x3 conv
    pvconv_kernel<<<1792, 256, 0, stream>>>(Qb, Kb, Vt, ps, xpart, Ypad, wr, b3, Y3);
    // 5. reduce xpart over ks (once)
    xreduce_kernel<<<192, 256, 0, stream>>>(xpart, xsum);
    // 6. both output halves (z uses S + PE inline)
    zy_out_kernel<<<512, 256, 0, stream>>>(xsum, w_o, b_o, g_o, be_o, S,
                                           Y3, w_y2, b_y2, g_y2, be_y2, out);
}